// Round 11
// baseline (85.610 us; speedup 1.0000x reference)
//
#include <hip/hip_runtime.h>

typedef float v2f __attribute__((ext_vector_type(2)));

constexpr int S = 512, B = 8192, H = 5;
constexpr float KN1 = -1.44269504088896340736f;   // -log2(e)
constexpr float KN2 = 2.0f * KN1;                 // -2*log2(e)

__device__ __forceinline__ float fexp2(float x) { return __builtin_amdgcn_exp2f(x); }
__device__ __forceinline__ float frcp(float x)  { return __builtin_amdgcn_rcpf(x); }
__device__ __forceinline__ v2f fma2(v2f a, v2f b, v2f c) { return __builtin_elementwise_fma(a, b, c); }

// Magic-seed Newton reciprocal: ~28 cy of FMA-chain latency instead of
// ~60 cy v_rcp trans latency. Seed rel err ~5%; 2 Newtons -> ~6e-6.
__device__ __forceinline__ float nrcp(float d) {
  float s = __int_as_float(0x7EF311C3 - __float_as_int(d));
  s = s * fmaf(-d, s, 2.0f);
  s = s * fmaf(-d, s, 2.0f);
  return s;
}

// ds_swizzle (epilogue reduction only): imm = xor<<10 | or<<5 | and
#define SWZ(v, imm) __int_as_float(__builtin_amdgcn_ds_swizzle(__float_as_int(v), (imm)))
// DPP (VALU pipe), in-group for 8-aligned 8-lane groups.
#define DPP(v, ctrl) __int_as_float(__builtin_amdgcn_mov_dpp(__float_as_int(v), (ctrl), 0xF, 0xF, false))

// CYCLE-MINIMIZATION (R10 lesson: time = S * dependency-cycle; issue is
// irrelevant at ~50% VALUBusy). R10 cycle had 4 trans latencies:
// exp2(a)->rcp(den)->c->exp2(CS)->rcp(Dc). This kernel keeps the 2
// irreducible exp2's and replaces both rcp's with magic+2-Newton (FMA
// latency). Cell state kept as UNNORMALIZED numerator:
//   numK = KN2*c*den,  R3 = 1/den  (den = Df*Di*Dg)
//   numK' = numK*(R3*P') + KN2*(1-Eg')*Df'     (exact; P' = Di'*Dg')
//   CS    = numK'*R3'  (= c'*KN2), tanh via Ec=exp2(CS)
//   h     = (1-Ec)*rcp(Do)*nrcp(1+Ec)
// Layout = R9/R10: 8 lanes/chain, lane j owns unit j wholly (lanes 5-7
// duplicate unit 4); only cross-lane op is the DPP h-broadcast.
// 8192 chains * 8 = 65536 threads = 1024 waves = 1 wave/SIMD.
__global__ __launch_bounds__(256, 1) void lstm_kernel(
    const float* __restrict__ x,      // [S,B,2]
    const float* __restrict__ W_ih,   // [4H,2]
    const float* __restrict__ W_hh,   // [4H,H]
    const float* __restrict__ b_ih,   // [4H]
    const float* __restrict__ b_hh,   // [4H]
    const float* __restrict__ W_lin,  // [1,H]
    const float* __restrict__ b_lin,  // [1]
    float* __restrict__ out)          // [B,1]
{
  const int tid   = blockIdx.x * blockDim.x + threadIdx.x;
  const int chain = tid >> 3;
  const int j     = tid & 7;
  const int jm    = (j < H) ? j : H - 1;

  const int ri = jm, rf = H + jm, rg = 2 * H + jm, ro = 3 * H + jm;

  // acc1 = {i-row, f-row} (KN1); acc2 = {g-row (KN2), o-row (KN1)}.
  const v2f wx0_1 = {W_ih[ri * 2 + 0] * KN1, W_ih[rf * 2 + 0] * KN1};
  const v2f wx1_1 = {W_ih[ri * 2 + 1] * KN1, W_ih[rf * 2 + 1] * KN1};
  const v2f wx0_2 = {W_ih[rg * 2 + 0] * KN2, W_ih[ro * 2 + 0] * KN1};
  const v2f wx1_2 = {W_ih[rg * 2 + 1] * KN2, W_ih[ro * 2 + 1] * KN1};
  v2f wh1[H], wh2[H];
  #pragma unroll
  for (int k = 0; k < H; ++k) {
    wh1[k] = (v2f){W_hh[ri * H + k] * KN1, W_hh[rf * H + k] * KN1};
    wh2[k] = (v2f){W_hh[rg * H + k] * KN2, W_hh[ro * H + k] * KN1};
  }
  const v2f bb1 = {(b_ih[ri] + b_hh[ri]) * KN1, (b_ih[rf] + b_hh[rf]) * KN1};
  const v2f bb2 = {(b_ih[rg] + b_hh[rg]) * KN2, (b_ih[ro] + b_hh[ro]) * KN1};

  float numK = 0.0f;   // KN2 * c * den   (c0 = 0)
  float R3   = 1.0f;   // 1/den           (den0 = 1)
  float h    = 0.0f;
  float hg[H] = {0, 0, 0, 0, 0};

  const float2* __restrict__ x2 = (const float2*)x;

  auto step = [&](float2 xv) {
    // Base pre-activations (off-cycle) + tree-form h-dot (short depth).
    v2f a1 = bb1, a2 = bb2;
    a1 = fma2((v2f){xv.x, xv.x}, wx0_1, a1);
    a2 = fma2((v2f){xv.x, xv.x}, wx0_2, a2);
    a1 = fma2((v2f){xv.y, xv.y}, wx1_1, a1);
    a2 = fma2((v2f){xv.y, xv.y}, wx1_2, a2);
    const v2f h0 = {hg[0], hg[0]}, h1 = {hg[1], hg[1]}, h2v = {hg[2], hg[2]},
              h3 = {hg[3], hg[3]}, h4 = {hg[4], hg[4]};
    const v2f pA1 = fma2(h1, wh1[1], h0 * wh1[0]);
    const v2f pB1 = fma2(h3, wh1[3], h2v * wh1[2]);
    const v2f pC1 = fma2(h4, wh1[4], a1);
    a1 = (pA1 + pB1) + pC1;
    const v2f pA2 = fma2(h1, wh2[1], h0 * wh2[0]);
    const v2f pB2 = fma2(h3, wh2[3], h2v * wh2[2]);
    const v2f pC2 = fma2(h4, wh2[4], a2);
    a2 = (pA2 + pB2) + pC2;

    // Gate exponentials (1st trans latency on cycle).
    const float Ei = fexp2(a1.x);
    const float Ef = fexp2(a1.y);
    const float Eg = fexp2(a2.x);
    const float Eo = fexp2(a2.y);
    const float Di = 1.0f + Ei, Df = 1.0f + Ef;
    const float Dg = 1.0f + Eg, Do = 1.0f + Eo;
    const float P   = Di * Dg;
    const float den = P * Df;
    const float R3P = R3 * P;                        // prev-step R3
    const float gnum = fmaf(-KN2, Eg, KN2) * Df;     // KN2*(1-Eg)*Df
    numK = fmaf(numK, R3P, gnum);                    // KN2*c'*den'
    R3 = nrcp(den);                                  // FMA-latency rcp
    const float so = frcp(Do);                       // off-cycle HW rcp
    float CS = numK * R3;                            // c'*KN2
    CS = fminf(fmaxf(CS, -88.0f), 88.0f);            // NaN insurance
    // tanh (2nd trans latency) + Newton rcp.
    const float Ec = fexp2(CS);
    const float Dc = 1.0f + Ec;
    const float Tn = 1.0f - Ec;
    const float Rc = nrcp(Dc);
    h = (Tn * so) * Rc;                              // o * tanh(c)
    // h-broadcast via DPP (VALU pipe); lanes 4-7 all hold h4 (dups).
    const bool hi = (j & 4) != 0;
    const float hm = DPP(h, 0x141);                  // half-mirror
    hg[4] = hi ? h : hm;
    const float s0 = DPP(h, 0x00), m0 = DPP(s0, 0x141);
    hg[0] = hi ? m0 : s0;
    const float s1 = DPP(h, 0x55), m1 = DPP(s1, 0x141);
    hg[1] = hi ? m1 : s1;
    const float s2 = DPP(h, 0xAA), m2 = DPP(s2, 0x141);
    hg[2] = hi ? m2 : s2;
    const float s3 = DPP(h, 0xFF), m3 = DPP(s3, 0x141);
    hg[3] = hi ? m3 : s3;
  };

  // Ping-pong register prefetch of x, 4 steps deep.
  constexpr int CH = 4;
  float2 buf0[CH], buf1[CH];
  #pragma unroll
  for (int t = 0; t < CH; ++t) buf0[t] = x2[(size_t)t * B + chain];

  for (int t0 = 0; t0 < S; t0 += 2 * CH) {
    #pragma unroll
    for (int t = 0; t < CH; ++t) buf1[t] = x2[(size_t)(t0 + CH + t) * B + chain];
    #pragma unroll
    for (int t = 0; t < CH; ++t) step(buf0[t]);
    if (t0 + 2 * CH < S) {
      #pragma unroll
      for (int t = 0; t < CH; ++t) buf0[t] = x2[(size_t)(t0 + 2 * CH + t) * B + chain];
    }
    #pragma unroll
    for (int t = 0; t < CH; ++t) step(buf1[t]);
  }

  // out[chain] = sum_j h_j*W_lin[j] + b_lin (butterfly within 8 lanes).
  float pv = (j < H) ? h * W_lin[jm] : 0.0f;
  pv += SWZ(pv, 0x041F);   // xor 1
  pv += SWZ(pv, 0x081F);   // xor 2
  pv += SWZ(pv, 0x101F);   // xor 4
  if (j == 0) out[chain] = pv + b_lin[0];
}

extern "C" void kernel_launch(void* const* d_in, const int* in_sizes, int n_in,
                              void* d_out, int out_size, void* d_ws, size_t ws_size,
                              hipStream_t stream) {
  const float* x     = (const float*)d_in[0];
  const float* W_ih  = (const float*)d_in[1];
  const float* W_hh  = (const float*)d_in[2];
  const float* b_ih  = (const float*)d_in[3];
  const float* b_hh  = (const float*)d_in[4];
  const float* W_lin = (const float*)d_in[5];
  const float* b_lin = (const float*)d_in[6];
  float* out = (float*)d_out;

  const int threads = B * 8;           // 65536 -> 1024 waves -> 1/SIMD
  dim3 grid(threads / 256), block(256);
  hipLaunchKernelGGL(lstm_kernel, grid, block, 0, stream,
                     x, W_ih, W_hh, b_ih, b_hh, W_lin, b_lin, out);
}

// Round 13
// 78.492 us; speedup vs baseline: 1.0907x; 1.0907x over previous
//
#include <hip/hip_runtime.h>

typedef float v2f __attribute__((ext_vector_type(2)));

constexpr int S = 512, B = 8192, H = 5;
constexpr float KN1 = -1.44269504088896340736f;   // -log2(e)
constexpr float KN2 = 2.0f * KN1;                 // -2*log2(e)

__device__ __forceinline__ float fexp2(float x) { return __builtin_amdgcn_exp2f(x); }
__device__ __forceinline__ float frcp(float x)  { return __builtin_amdgcn_rcpf(x); }

// ds_swizzle (epilogue reduction only): imm = xor<<10 | or<<5 | and
#define SWZ(v, imm) __int_as_float(__builtin_amdgcn_ds_swizzle(__float_as_int(v), (imm)))
// DPP (VALU pipe), in-group for 8-aligned 8-lane groups:
//   quad_perm[k,k,k,k] (ctrl k*0x55): broadcast lane k of each 4-quad
//   row_half_mirror (ctrl 0x141):     lane l <-> (l&~7)|(7-(l&7))
#define DPP(v, ctrl) __int_as_float(__builtin_amdgcn_mov_dpp(__float_as_int(v), (ctrl), 0xF, 0xF, false))

// R10 base (best: 73.6us) + ONE change: the final tanh normalization
// rcp(Do*Dc) [on the dependency cycle] -> range-restricted Newton rcp.
// Symmetrize: CSn = -|CS| -> Ec = exp2(CSn) in (0,1], Dc in (1,2].
// Seed for d in [1,2] is 24/17 - 8/17*d  (R12 bug: used the [0.5,1]
// seed 48/17 - 32/17*d, which goes NEGATIVE for d>1.5 -> Newton
// diverges; d=2 is the common c~0 case). Max rel err 1/17; 2 Newtons
// -> 1.2e-5. rcp(Do) is off-path (hidden under exp2 slack); tanh sign
// = -sign(CS), folded into so off-path.
// Everything else identical to R10: common-denominator gates (7 trans),
// 8 lanes/chain, lane j owns unit j wholly, DPP-only h-broadcast,
// 1024 waves = 1 wave/SIMD.
__global__ __launch_bounds__(256, 1) void lstm_kernel(
    const float* __restrict__ x,      // [S,B,2]
    const float* __restrict__ W_ih,   // [4H,2]
    const float* __restrict__ W_hh,   // [4H,H]
    const float* __restrict__ b_ih,   // [4H]
    const float* __restrict__ b_hh,   // [4H]
    const float* __restrict__ W_lin,  // [1,H]
    const float* __restrict__ b_lin,  // [1]
    float* __restrict__ out)          // [B,1]
{
  const int tid   = blockIdx.x * blockDim.x + threadIdx.x;
  const int chain = tid >> 3;
  const int j     = tid & 7;
  const int jm    = (j < H) ? j : H - 1;

  const int ri = jm, rf = H + jm, rg = 2 * H + jm, ro = 3 * H + jm;

  // acc1 = {i-row, f-row} (KN1); acc2 = {g-row (KN2), o-row (KN1)}.
  const v2f wx0_1 = {W_ih[ri * 2 + 0] * KN1, W_ih[rf * 2 + 0] * KN1};
  const v2f wx1_1 = {W_ih[ri * 2 + 1] * KN1, W_ih[rf * 2 + 1] * KN1};
  const v2f wx0_2 = {W_ih[rg * 2 + 0] * KN2, W_ih[ro * 2 + 0] * KN1};
  const v2f wx1_2 = {W_ih[rg * 2 + 1] * KN2, W_ih[ro * 2 + 1] * KN1};
  v2f wh1[H], wh2[H];
  #pragma unroll
  for (int k = 0; k < H; ++k) {
    wh1[k] = (v2f){W_hh[ri * H + k] * KN1, W_hh[rf * H + k] * KN1};
    wh2[k] = (v2f){W_hh[rg * H + k] * KN2, W_hh[ro * H + k] * KN1};
  }
  const v2f bb1 = {(b_ih[ri] + b_hh[ri]) * KN1, (b_ih[rf] + b_hh[rf]) * KN1};
  const v2f bb2 = {(b_ih[rg] + b_hh[rg]) * KN2, (b_ih[ro] + b_hh[ro]) * KN1};

  float CS = 0.0f, h = 0.0f;          // CS = c*KN2 (scaled cell state)
  float hg[H] = {0, 0, 0, 0, 0};      // broadcast h vector

  const float2* __restrict__ x2 = (const float2*)x;

  auto step = [&](float2 xv) {
    v2f a1 = bb1, a2 = bb2;
    a1 = __builtin_elementwise_fma((v2f){xv.x, xv.x}, wx0_1, a1);
    a2 = __builtin_elementwise_fma((v2f){xv.x, xv.x}, wx0_2, a2);
    a1 = __builtin_elementwise_fma((v2f){xv.y, xv.y}, wx1_1, a1);
    a2 = __builtin_elementwise_fma((v2f){xv.y, xv.y}, wx1_2, a2);
    #pragma unroll
    for (int k = 0; k < H; ++k) {
      a1 = __builtin_elementwise_fma((v2f){hg[k], hg[k]}, wh1[k], a1);
      a2 = __builtin_elementwise_fma((v2f){hg[k], hg[k]}, wh2[k], a2);
    }
    // Gate exponentials + common-denominator sigma/tanh (as R10).
    const float Ei = fexp2(a1.x);
    const float Ef = fexp2(a1.y);
    const float Eg = fexp2(a2.x);
    const float Eo = fexp2(a2.y);
    const float Di = 1.0f + Ei, Df = 1.0f + Ef;
    const float Dg = 1.0f + Eg, Do = 1.0f + Eo;
    const float P   = Di * Dg;
    const float R3v = frcp(P * Df);                  // 1/(Df*Di*Dg)
    const float so  = frcp(Do);                      // off-path (full slack)
    const float gnum = fmaf(-KN2, Eg, KN2) * Df;     // KN2*(1-Eg)*Df
    const float num  = fmaf(CS, P, gnum);
    CS = num * R3v;                                  // (f*c + i*g)*KN2
    // Symmetrized tanh: CSn = -|CS| -> Dc in (1,2].
    const float CSn = __int_as_float(__float_as_int(CS) | 0x80000000);
    const float Ec = fexp2(CSn);                     // (0,1]
    const float Dc = 1.0f + Ec;                      // (1,2]
    const float Tn = 1.0f - Ec;                      // |tanh|*Dc
    // rcp(Dc), d in [1,2]: seed 24/17 - 8/17*d + 2 Newtons (~1.2e-5).
    float s = fmaf(Dc, -8.0f / 17.0f, 24.0f / 17.0f);
    s = s * fmaf(-Dc, s, 2.0f);
    s = s * fmaf(-Dc, s, 2.0f);
    // tanh sign = sign(c) = -sign(CS); fold into so (off-path select).
    const float osgn = (CS <= 0.0f) ? so : -so;
    h = (Tn * osgn) * s;                             // o * tanh(c)
    // h-broadcast via DPP (VALU pipe); lanes 4-7 all hold h4 (dups).
    const bool hi = (j & 4) != 0;
    const float hm = DPP(h, 0x141);                  // half-mirror
    hg[4] = hi ? h : hm;
    const float s0 = DPP(h, 0x00), m0 = DPP(s0, 0x141);
    hg[0] = hi ? m0 : s0;
    const float s1 = DPP(h, 0x55), m1 = DPP(s1, 0x141);
    hg[1] = hi ? m1 : s1;
    const float s2 = DPP(h, 0xAA), m2 = DPP(s2, 0x141);
    hg[2] = hi ? m2 : s2;
    const float s3 = DPP(h, 0xFF), m3 = DPP(s3, 0x141);
    hg[3] = hi ? m3 : s3;
  };

  // Ping-pong register prefetch of x, 4 steps deep.
  constexpr int CH = 4;
  float2 buf0[CH], buf1[CH];
  #pragma unroll
  for (int t = 0; t < CH; ++t) buf0[t] = x2[(size_t)t * B + chain];

  for (int t0 = 0; t0 < S; t0 += 2 * CH) {
    #pragma unroll
    for (int t = 0; t < CH; ++t) buf1[t] = x2[(size_t)(t0 + CH + t) * B + chain];
    #pragma unroll
    for (int t = 0; t < CH; ++t) step(buf0[t]);
    if (t0 + 2 * CH < S) {
      #pragma unroll
      for (int t = 0; t < CH; ++t) buf0[t] = x2[(size_t)(t0 + 2 * CH + t) * B + chain];
    }
    #pragma unroll
    for (int t = 0; t < CH; ++t) step(buf1[t]);
  }

  // out[chain] = sum_j h_j*W_lin[j] + b_lin (butterfly within 8 lanes).
  float pv = (j < H) ? h * W_lin[jm] : 0.0f;
  pv += SWZ(pv, 0x041F);   // xor 1
  pv += SWZ(pv, 0x081F);   // xor 2
  pv += SWZ(pv, 0x101F);   // xor 4
  if (j == 0) out[chain] = pv + b_lin[0];
}

extern "C" void kernel_launch(void* const* d_in, const int* in_sizes, int n_in,
                              void* d_out, int out_size, void* d_ws, size_t ws_size,
                              hipStream_t stream) {
  const float* x     = (const float*)d_in[0];
  const float* W_ih  = (const float*)d_in[1];
  const float* W_hh  = (const float*)d_in[2];
  const float* b_ih  = (const float*)d_in[3];
  const float* b_hh  = (const float*)d_in[4];
  const float* W_lin = (const float*)d_in[5];
  const float* b_lin = (const float*)d_in[6];
  float* out = (float*)d_out;

  const int threads = B * 8;           // 65536 -> 1024 waves -> 1/SIMD
  dim3 grid(threads / 256), block(256);
  hipLaunchKernelGGL(lstm_kernel, grid, block, 0, stream,
                     x, W_ih, W_hh, b_ih, b_hh, W_lin, b_lin, out);
}

// Round 14
// 73.384 us; speedup vs baseline: 1.1666x; 1.0696x over previous
//
#include <hip/hip_runtime.h>

typedef float v2f __attribute__((ext_vector_type(2)));

constexpr int S = 512, B = 8192, H = 5;
constexpr float KN1 = -1.44269504088896340736f;   // -log2(e)
constexpr float KN2 = 2.0f * KN1;                 // -2*log2(e)

__device__ __forceinline__ float fexp2(float x) { return __builtin_amdgcn_exp2f(x); }
__device__ __forceinline__ float frcp(float x)  { return __builtin_amdgcn_rcpf(x); }

// ds_swizzle (epilogue reduction only): imm = xor<<10 | or<<5 | and
#define SWZ(v, imm) __int_as_float(__builtin_amdgcn_ds_swizzle(__float_as_int(v), (imm)))
// DPP (VALU pipe), in-group for 8-aligned 8-lane groups:
//   quad_perm[k,k,k,k] (ctrl k*0x55): broadcast lane k of each 4-quad
//   row_half_mirror (ctrl 0x141):     lane l <-> (l&~7)|(7-(l&7))
#define DPP(v, ctrl) __int_as_float(__builtin_amdgcn_mov_dpp(__float_as_int(v), (ctrl), 0xF, 0xF, false))

// FINAL (R10 verbatim, session best: 73.6 us = 2.77x over R1 baseline).
// Structure: 8 lanes/chain, lane j owns hidden unit j WHOLLY (all four
// gates i,f,g,o + cell state + h; lanes 5-7 duplicate unit 4 bitwise).
// The only cross-lane op is the h-broadcast via quad_perm/half-mirror DPP
// (VALU pipe). Gate math uses common-denominator algebra (7 trans/step):
//   E* = exp2(-z* log2e) (g,c rows at -2 log2e), D* = 1+E*
//   c' = [c*Di*Dg + (1-Eg)*Df] / (Df*Di*Dg)   -> 3 exp2 + 1 rcp
//   h  = o*tanh(c') = (1-Ec)/(Do*Dc)          -> 2 exp2 + 2 rcp (so off-path)
// Cell state kept scaled (CS = c*KN2) so Ec = exp2(CS) directly.
// 8192 chains * 8 = 65536 threads = 1024 waves = 1 wave/SIMD.
// Perf is the serial-recurrence latency floor: 512 steps x ~345 cy
// dependency cycle (2 exp2 + 2 rcp dependent latencies + h-dot feedback);
// R11/R13 proved Newton-rcp substitution regresses, R2-R9 proved all
// alternative lane decompositions regress.
__global__ __launch_bounds__(256, 1) void lstm_kernel(
    const float* __restrict__ x,      // [S,B,2]
    const float* __restrict__ W_ih,   // [4H,2]
    const float* __restrict__ W_hh,   // [4H,H]
    const float* __restrict__ b_ih,   // [4H]
    const float* __restrict__ b_hh,   // [4H]
    const float* __restrict__ W_lin,  // [1,H]
    const float* __restrict__ b_lin,  // [1]
    float* __restrict__ out)          // [B,1]
{
  const int tid   = blockIdx.x * blockDim.x + threadIdx.x;
  const int chain = tid >> 3;
  const int j     = tid & 7;
  const int jm    = (j < H) ? j : H - 1;

  const int ri = jm, rf = H + jm, rg = 2 * H + jm, ro = 3 * H + jm;

  // acc1 = {i-row, f-row} (KN1); acc2 = {g-row (KN2), o-row (KN1)}.
  const v2f wx0_1 = {W_ih[ri * 2 + 0] * KN1, W_ih[rf * 2 + 0] * KN1};
  const v2f wx1_1 = {W_ih[ri * 2 + 1] * KN1, W_ih[rf * 2 + 1] * KN1};
  const v2f wx0_2 = {W_ih[rg * 2 + 0] * KN2, W_ih[ro * 2 + 0] * KN1};
  const v2f wx1_2 = {W_ih[rg * 2 + 1] * KN2, W_ih[ro * 2 + 1] * KN1};
  v2f wh1[H], wh2[H];
  #pragma unroll
  for (int k = 0; k < H; ++k) {
    wh1[k] = (v2f){W_hh[ri * H + k] * KN1, W_hh[rf * H + k] * KN1};
    wh2[k] = (v2f){W_hh[rg * H + k] * KN2, W_hh[ro * H + k] * KN1};
  }
  const v2f bb1 = {(b_ih[ri] + b_hh[ri]) * KN1, (b_ih[rf] + b_hh[rf]) * KN1};
  const v2f bb2 = {(b_ih[rg] + b_hh[rg]) * KN2, (b_ih[ro] + b_hh[ro]) * KN1};

  float CS = 0.0f, h = 0.0f;          // CS = c*KN2 (scaled cell state)
  float hg[H] = {0, 0, 0, 0, 0};      // broadcast h vector

  const float2* __restrict__ x2 = (const float2*)x;

  auto step = [&](float2 xv) {
    v2f a1 = bb1, a2 = bb2;
    a1 = __builtin_elementwise_fma((v2f){xv.x, xv.x}, wx0_1, a1);
    a2 = __builtin_elementwise_fma((v2f){xv.x, xv.x}, wx0_2, a2);
    a1 = __builtin_elementwise_fma((v2f){xv.y, xv.y}, wx1_1, a1);
    a2 = __builtin_elementwise_fma((v2f){xv.y, xv.y}, wx1_2, a2);
    #pragma unroll
    for (int k = 0; k < H; ++k) {
      a1 = __builtin_elementwise_fma((v2f){hg[k], hg[k]}, wh1[k], a1);
      a2 = __builtin_elementwise_fma((v2f){hg[k], hg[k]}, wh2[k], a2);
    }
    // 5 exp2 + 2 rcp per step.
    const float Ei = fexp2(a1.x);
    const float Ef = fexp2(a1.y);
    const float Eg = fexp2(a2.x);
    const float Eo = fexp2(a2.y);
    const float Di = 1.0f + Ei, Df = 1.0f + Ef;
    const float Dg = 1.0f + Eg, Do = 1.0f + Eo;
    const float P   = Di * Dg;
    const float R3v = frcp(P * Df);                  // 1/(Df*Di*Dg)
    // KN2*(1-Eg) = fma(-KN2, Eg, KN2); scaled numerator keeps CS = c*KN2.
    const float gnum = fmaf(-KN2, Eg, KN2) * Df;     // KN2*(1-Eg)*Df
    const float num  = fmaf(CS, P, gnum);
    CS = num * R3v;                                  // (f*c + i*g)*KN2
    const float Ec = fexp2(CS);                      // exp(-2c)
    const float Dc = 1.0f + Ec;
    const float Rh = frcp(Do * Dc);
    h = (1.0f - Ec) * Rh;                            // o * tanh(c)
    // h-broadcast via DPP (VALU pipe); lanes 4-7 all hold h4 (dups).
    const bool hi = (j & 4) != 0;
    const float hm = DPP(h, 0x141);                  // half-mirror
    hg[4] = hi ? h : hm;
    const float s0 = DPP(h, 0x00), m0 = DPP(s0, 0x141);
    hg[0] = hi ? m0 : s0;
    const float s1 = DPP(h, 0x55), m1 = DPP(s1, 0x141);
    hg[1] = hi ? m1 : s1;
    const float s2 = DPP(h, 0xAA), m2 = DPP(s2, 0x141);
    hg[2] = hi ? m2 : s2;
    const float s3 = DPP(h, 0xFF), m3 = DPP(s3, 0x141);
    hg[3] = hi ? m3 : s3;
  };

  // Ping-pong register prefetch of x, 4 steps deep.
  constexpr int CH = 4;
  float2 buf0[CH], buf1[CH];
  #pragma unroll
  for (int t = 0; t < CH; ++t) buf0[t] = x2[(size_t)t * B + chain];

  for (int t0 = 0; t0 < S; t0 += 2 * CH) {
    #pragma unroll
    for (int t = 0; t < CH; ++t) buf1[t] = x2[(size_t)(t0 + CH + t) * B + chain];
    #pragma unroll
    for (int t = 0; t < CH; ++t) step(buf0[t]);
    if (t0 + 2 * CH < S) {
      #pragma unroll
      for (int t = 0; t < CH; ++t) buf0[t] = x2[(size_t)(t0 + 2 * CH + t) * B + chain];
    }
    #pragma unroll
    for (int t = 0; t < CH; ++t) step(buf1[t]);
  }

  // out[chain] = sum_j h_j*W_lin[j] + b_lin (butterfly within 8 lanes).
  float pv = (j < H) ? h * W_lin[jm] : 0.0f;
  pv += SWZ(pv, 0x041F);   // xor 1
  pv += SWZ(pv, 0x081F);   // xor 2
  pv += SWZ(pv, 0x101F);   // xor 4
  if (j == 0) out[chain] = pv + b_lin[0];
}

extern "C" void kernel_launch(void* const* d_in, const int* in_sizes, int n_in,
                              void* d_out, int out_size, void* d_ws, size_t ws_size,
                              hipStream_t stream) {
  const float* x     = (const float*)d_in[0];
  const float* W_ih  = (const float*)d_in[1];
  const float* W_hh  = (const float*)d_in[2];
  const float* b_ih  = (const float*)d_in[3];
  const float* b_hh  = (const float*)d_in[4];
  const float* W_lin = (const float*)d_in[5];
  const float* b_lin = (const float*)d_in[6];
  float* out = (float*)d_out;

  const int threads = B * 8;           // 65536 -> 1024 waves -> 1/SIMD
  dim3 grid(threads / 256), block(256);
  hipLaunchKernelGGL(lstm_kernel, grid, block, 0, stream,
                     x, W_ih, W_hh, b_ih, b_hh, W_lin, b_lin, out);
}